// Round 1
// 887.173 us; speedup vs baseline: 1.0122x; 1.0122x over previous
//
#include <hip/hip_runtime.h>
#include <hip/hip_bf16.h>
#include <cstdint>
#include <cstddef>

#define NUSER 50000
#define NITEM 40000
#define NNODE 90000
#define NE    1000000
#define DIM   64
#define CAP   16    // LDS-cached neighbor rows per user wave (P(deg>16)~3%, guarded fallback)
#define ESTN  32    // per-wave e-stash capacity (edges); P(deg>32)~0

typedef __attribute__((ext_vector_type(8))) short short8;
typedef __attribute__((ext_vector_type(4))) float f32x4;

// ---------------- workspace layout (float element offsets) ----------------
constexpr size_t O_XVT  = 0;           // ushort[90000*128]
constexpr size_t O_X0   = 5760000;     // float [90000*64]
constexpr size_t O_X0B  = 11520000;    // ushort[90000*64]
constexpr size_t O_H1B  = 14400000;    // ushort[90000*64]
constexpr size_t O_XVF  = 17280000;    // float [40000*64]
constexpr size_t O_XTF  = 19840000;    // float [40000*64]
constexpr size_t O_AE   = 22400000;    // float [1M]
constexpr size_t O_BE   = 23400000;    // float [1M]
constexpr size_t O_WE   = 24400000;    // float [1M]
constexpr size_t O_SV   = 25400000;    // float [90000]
constexpr size_t O_ST   = 25490000;    // float [90000]
constexpr size_t O_DEG  = 25580000;    // int [90000]
constexpr size_t O_RP   = 25670000;    // int [90001]
constexpr size_t O_FILL = 25770000;    // int [90000]
constexpr size_t O_SRC  = 25870000;    // int [1M]
constexpr size_t O_BSUM = 26870000;    // int [512]
constexpr size_t O_WSPL = 26880000;    // shorts (~312k)
constexpr size_t O_PV   = 27040000;    // float [4*40000*64] gemm-v partials
constexpr size_t O_PT   = 37280000;    // float [40000*64]   gemm-t partial
// split-W offsets within O_WSPL, in shorts:
constexpr size_t SW_VHI = 0;
constexpr size_t SW_VLO = 131072;
constexpr size_t SW_THI = 262144;
constexpr size_t SW_TLO = 286720;

// mega_prep block classes
#define B_GV 2500   // gemm_v: 4 segs x 625
#define B_GT 625
#define B_DC 1024
#define B_LN 1024
#define BASE_GT 2500
#define BASE_DC 3125
#define BASE_LN 4149
#define MEGA_BLOCKS 5173

__device__ __forceinline__ float leaky(float x) { return x >= 0.f ? x : 0.01f * x; }

__device__ __forceinline__ unsigned short f2bfu(float x) {
  __hip_bfloat16 h = __float2bfloat16(x);
  return *reinterpret_cast<unsigned short*>(&h);
}
__device__ __forceinline__ short f2bf(float x) { return (short)f2bfu(x); }
__device__ __forceinline__ float bf2f(short s) {
  unsigned int u = ((unsigned int)(unsigned short)s) << 16;
  return __uint_as_float(u);
}
__device__ __forceinline__ void bf8_to_f32(uint4 u, float* f) {
  f[0] = __uint_as_float(u.x << 16); f[1] = __uint_as_float(u.x & 0xffff0000u);
  f[2] = __uint_as_float(u.y << 16); f[3] = __uint_as_float(u.y & 0xffff0000u);
  f[4] = __uint_as_float(u.z << 16); f[5] = __uint_as_float(u.z & 0xffff0000u);
  f[6] = __uint_as_float(u.w << 16); f[7] = __uint_as_float(u.w & 0xffff0000u);
}
__device__ __forceinline__ uint4 f32_to_bf8(const float* f) {
  uint4 u;
  u.x = (uint32_t)f2bfu(f[0]) | ((uint32_t)f2bfu(f[1]) << 16);
  u.y = (uint32_t)f2bfu(f[2]) | ((uint32_t)f2bfu(f[3]) << 16);
  u.z = (uint32_t)f2bfu(f[4]) | ((uint32_t)f2bfu(f[5]) << 16);
  u.w = (uint32_t)f2bfu(f[6]) | ((uint32_t)f2bfu(f[7]) << 16);
  return u;
}
__device__ __forceinline__ void bf4_to_f32(uint2 u, float* f) {
  f[0] = __uint_as_float(u.x << 16); f[1] = __uint_as_float(u.x & 0xffff0000u);
  f[2] = __uint_as_float(u.y << 16); f[3] = __uint_as_float(u.y & 0xffff0000u);
}
__device__ __forceinline__ uint2 f32_to_bf4(const float* f) {
  uint2 u;
  u.x = (uint32_t)f2bfu(f[0]) | ((uint32_t)f2bfu(f[1]) << 16);
  u.y = (uint32_t)f2bfu(f[2]) | ((uint32_t)f2bfu(f[3]) << 16);
  return u;
}

// async global->LDS, 16B per lane (wave-uniform LDS base + lane*16; per-lane global src)
__device__ __forceinline__ void gld_lds16(const void* g, void* l) {
  __builtin_amdgcn_global_load_lds(
      (const __attribute__((address_space(1))) unsigned int*)g,
      (__attribute__((address_space(3))) unsigned int*)l, 16, 0, 0);
}

// ---------------- W split: fp32 -> bf16 hi/lo, MFMA-fragment-linear --------
__global__ __launch_bounds__(256) void wsplit_all_kernel(const float* __restrict__ Wv,
                                                         const float* __restrict__ Wt,
                                                         short* __restrict__ base) {
  int t = blockIdx.x * 256 + threadIdx.x;
  const int NV = 2048 * 64, NT = 384 * 64;
  const float* W;
  short *hi, *lo;
  int idx;
  if (t < NV) { W = Wv; hi = base + SW_VHI; lo = base + SW_VLO; idx = t; }
  else if (t < NV + NT) { W = Wt; hi = base + SW_THI; lo = base + SW_TLO; idx = t - NV; }
  else return;
  int j = idx & 7, sl = (idx >> 3) & 15, q = (idx >> 7) & 3, nt = (idx >> 9) & 3, kt = idx >> 11;
  int k = kt * 32 + q * 8 + j, n = nt * 16 + sl;
  float x = W[k * 64 + n];
  short h = f2bf(x);
  hi[idx] = h;
  lo[idx] = f2bf(x - bf2f(h));
}

// ---------------- GEMM partial (device fn, no epilogue) ----------------
__device__ __forceinline__ void gemm_partial(const float* __restrict__ A,
                                             const short* __restrict__ Whi,
                                             const short* __restrict__ Wlo,
                                             float* __restrict__ P, size_t prow0,
                                             short* Bsh, short* Bsl,
                                             int m0, int K, int kofs, int nchunk) {
  int tid = threadIdx.x;
  int w = tid >> 6, lane = tid & 63, q = lane >> 4, sl = lane & 15;
  const float* arow = A + (size_t)(m0 + w * 16 + sl) * K + kofs;
  f32x4 acc[4] = {{0.f, 0.f, 0.f, 0.f}, {0.f, 0.f, 0.f, 0.f},
                  {0.f, 0.f, 0.f, 0.f}, {0.f, 0.f, 0.f, 0.f}};
  for (int c = 0; c < nchunk; ++c) {
    __syncthreads();
    const short* srch = Whi + (size_t)c * 8192;
    const short* srcl = Wlo + (size_t)c * 8192;
#pragma unroll
    for (int r = 0; r < 4; ++r) {
      size_t off = (size_t)(r * 256 + w * 64) * 8;  // shorts; +lane*8 done by HW on LDS side
      gld_lds16(srch + off + lane * 8, Bsh + off);
      gld_lds16(srcl + off + lane * 8, Bsl + off);
    }
    __syncthreads();
#pragma unroll
    for (int kt = 0; kt < 4; ++kt) {
      int k = c * 128 + kt * 32 + q * 8;
      float4 a0 = *(const float4*)&arow[k];
      float4 a1 = *(const float4*)&arow[k + 4];
      float av[8] = {a0.x, a0.y, a0.z, a0.w, a1.x, a1.y, a1.z, a1.w};
      short8 ah, al;
#pragma unroll
      for (int j = 0; j < 8; ++j) {
        short h = f2bf(av[j]);
        ah[j] = h;
        al[j] = f2bf(av[j] - bf2f(h));
      }
#pragma unroll
      for (int nt = 0; nt < 4; ++nt) {
        short8 bh = *(short8*)&Bsh[(kt * 4 + nt) * 512 + lane * 8];
        short8 bl = *(short8*)&Bsl[(kt * 4 + nt) * 512 + lane * 8];
        acc[nt] = __builtin_amdgcn_mfma_f32_16x16x32_bf16(ah, bh, acc[nt], 0, 0, 0);
        acc[nt] = __builtin_amdgcn_mfma_f32_16x16x32_bf16(ah, bl, acc[nt], 0, 0, 0);
        acc[nt] = __builtin_amdgcn_mfma_f32_16x16x32_bf16(al, bh, acc[nt], 0, 0, 0);
      }
    }
  }
#pragma unroll
  for (int i = 0; i < 4; ++i) {
    int row = m0 + w * 16 + q * 4 + i;
#pragma unroll
    for (int nt = 0; nt < 4; ++nt)
      P[(prow0 + row) * 64 + nt * 16 + sl] = acc[nt][i];
  }
}

// ---------------- mega_prep: gemm_v(4 segs) | gemm_t | deg_count | id l2norm ----
__global__ __launch_bounds__(256) void mega_prep_kernel(
    const float* __restrict__ v_feat, const float* __restrict__ t_feat,
    const short* __restrict__ wsp,
    const int* __restrict__ ei, int* __restrict__ deg,
    const float* __restrict__ id_emb, float* __restrict__ x0,
    unsigned short* __restrict__ X0b,
    float* __restrict__ Pv, float* __restrict__ Pt) {
  __shared__ short Bsh[8192];
  __shared__ short Bsl[8192];
  int b = blockIdx.x;
  if (b < B_GV) {
    int seg = b / 625, m0 = (b % 625) * 64;
    gemm_partial(v_feat, wsp + SW_VHI + (size_t)seg * 4 * 8192,
                 wsp + SW_VLO + (size_t)seg * 4 * 8192,
                 Pv, (size_t)seg * 40000, Bsh, Bsl, m0, 2048, seg * 512, 4);
  } else if (b < BASE_DC) {
    int m0 = (b - BASE_GT) * 64;
    gemm_partial(t_feat, wsp + SW_THI, wsp + SW_TLO, Pt, 0, Bsh, Bsl, m0, 384, 0, 3);
  } else if (b < BASE_LN) {
    for (int e = (b - BASE_DC) * 256 + threadIdx.x; e < NE; e += B_DC * 256)
      atomicAdd(&deg[ei[NE + e]], 1);
  } else {
    int sl = threadIdx.x & 15;
    int qg = (b - BASE_LN) * 16 + (threadIdx.x >> 4);
    for (int r = qg; r < NNODE; r += B_LN * 16) {
      float4 v = *(const float4*)&id_emb[(size_t)r * 64 + sl * 4];
      float ss = v.x * v.x + v.y * v.y + v.z * v.z + v.w * v.w;
      ss += __shfl_xor(ss, 1); ss += __shfl_xor(ss, 2);
      ss += __shfl_xor(ss, 4); ss += __shfl_xor(ss, 8);
      float rinv = 1.f / fmaxf(sqrtf(ss), 1e-12f);
      float f[4] = {v.x * rinv, v.y * rinv, v.z * rinv, v.w * rinv};
      *(float4*)&x0[(size_t)r * 64 + sl * 4] = *(float4*)f;
      *(uint2*)&X0b[(size_t)r * 64 + sl * 4] = f32_to_bf4(f);
    }
  }
}

// ---------------- CSR scan (2 kernels) ----------------
__global__ __launch_bounds__(256) void scan_a_kernel(const int* __restrict__ deg,
                                                     int* __restrict__ bsum) {
  __shared__ int sd[4];
  int i = blockIdx.x * 256 + threadIdx.x;
  int v = (i < NNODE) ? deg[i] : 0;
#pragma unroll
  for (int off = 32; off > 0; off >>= 1) v += __shfl_xor(v, off, 64);
  if ((threadIdx.x & 63) == 0) sd[threadIdx.x >> 6] = v;
  __syncthreads();
  if (threadIdx.x == 0) bsum[blockIdx.x] = sd[0] + sd[1] + sd[2] + sd[3];
}

__global__ __launch_bounds__(256) void scan_b_kernel(const int* __restrict__ deg,
                                                     const int* __restrict__ bsum,
                                                     int* __restrict__ row_ptr,
                                                     int* __restrict__ fill) {
  __shared__ int s[256];
  __shared__ int sbase[4];
  int t = threadIdx.x, b = blockIdx.x;
  int v = (t < b) ? bsum[t] : 0;
  if (t + 256 < b) v += bsum[t + 256];
#pragma unroll
  for (int off = 32; off > 0; off >>= 1) v += __shfl_xor(v, off, 64);
  if ((t & 63) == 0) sbase[t >> 6] = v;
  int i = b * 256 + t;
  int d = (i < NNODE) ? deg[i] : 0;
  s[t] = d;
  __syncthreads();
  int base = sbase[0] + sbase[1] + sbase[2] + sbase[3];
  for (int off = 1; off < 256; off <<= 1) {
    int x = (t >= off) ? s[t - off] : 0;
    __syncthreads();
    s[t] += x;
    __syncthreads();
  }
  if (i < NNODE) {
    int excl = base + s[t] - d;
    row_ptr[i] = excl;
    fill[i] = excl;
    if (i == NNODE - 1) row_ptr[NNODE] = base + s[t];
  }
}

// ---------------- fill_epi: csr_fill | gemm epilogue ----------------
#define FE_FILL 512
__global__ __launch_bounds__(256) void fill_epi_kernel(
    const int* __restrict__ ei, int* __restrict__ fill, int* __restrict__ srcs,
    const float* __restrict__ Pv, const float* __restrict__ Pt,
    const float* __restrict__ b_v, const float* __restrict__ b_t,
    float* __restrict__ XVf, float* __restrict__ XTf,
    unsigned short* __restrict__ XVT) {
  int b = blockIdx.x;
  if (b < FE_FILL) {
    for (int e = b * 256 + threadIdx.x; e < NE; e += FE_FILL * 256) {
      int s = ei[e], d = ei[NE + e];
      int slot = atomicAdd(&fill[d], 1);
      srcs[slot] = s;
    }
    return;
  }
  int sl = threadIdx.x & 15;
  int q = (b - FE_FILL) * 16 + (threadIdx.x >> 4);  // 0..79999
  if (q >= 80000) return;
  int mod = q >= 40000;
  int r = q - mod * 40000;
  float4 a;
  if (!mod) {
    a = *(const float4*)&Pv[(size_t)r * 64 + sl * 4];
#pragma unroll
    for (int seg = 1; seg < 4; ++seg) {
      float4 p = *(const float4*)&Pv[((size_t)seg * 40000 + r) * 64 + sl * 4];
      a.x += p.x; a.y += p.y; a.z += p.z; a.w += p.w;
    }
  } else {
    a = *(const float4*)&Pt[(size_t)r * 64 + sl * 4];
  }
  float4 bias = *(const float4*)&(mod ? b_t : b_v)[sl * 4];
  float f[4] = {leaky(a.x + bias.x), leaky(a.y + bias.y),
                leaky(a.z + bias.z), leaky(a.w + bias.w)};
  float ss = f[0] * f[0] + f[1] * f[1] + f[2] * f[2] + f[3] * f[3];
  ss += __shfl_xor(ss, 1); ss += __shfl_xor(ss, 2);
  ss += __shfl_xor(ss, 4); ss += __shfl_xor(ss, 8);
  float rinv = 1.f / fmaxf(sqrtf(ss), 1e-12f);
#pragma unroll
  for (int k = 0; k < 4; ++k) f[k] *= rinv;
  *(float4*)&(mod ? XTf : XVf)[(size_t)r * 64 + sl * 4] = *(float4*)f;
  *(uint2*)&XVT[(size_t)(NUSER + r) * 128 + mod * 64 + sl * 4] = f32_to_bf4(f);
}

// ---------------- routing (3 iters) + user GAT + egcn_h1(user) ----------------
__global__ __launch_bounds__(256, 5) void routing_user_kernel(
    const float* __restrict__ pref_v, const float* __restrict__ pref_t,
    unsigned short* __restrict__ XVT, const unsigned short* __restrict__ X0b,
    const int* __restrict__ rp, const int* __restrict__ srcs,
    const float* __restrict__ conf,
    float* __restrict__ Ae, float* __restrict__ Be,
    float* __restrict__ SV, float* __restrict__ ST,
    float* __restrict__ wE, unsigned short* __restrict__ H1b,
    float* __restrict__ out) {
  __shared__ unsigned short cache[4][CAP * 128];
  __shared__ float estash[4][2 * ESTN];
  int wv = threadIdx.x >> 6;
  int u = blockIdx.x * 4 + wv;
  if (u >= NUSER) return;
  int lane = threadIdx.x & 63;
  int sub = lane >> 4, sl = lane & 15, half = sl >> 3, e8 = sl & 7;
  unsigned short* myc = cache[wv];
  float* es = estash[wv];

  const float* psrc = half ? pref_t : pref_v;
  float p[8];
  *(float4*)&p[0] = *(const float4*)&psrc[(size_t)u * 64 + e8 * 8];
  *(float4*)&p[4] = *(const float4*)&psrc[(size_t)u * 64 + e8 * 8 + 4];
  float ss = 0.f;
#pragma unroll
  for (int k = 0; k < 8; ++k) ss += p[k] * p[k];
  ss += __shfl_xor(ss, 1); ss += __shfl_xor(ss, 2); ss += __shfl_xor(ss, 4);
  float rinv = 1.f / fmaxf(sqrtf(ss), 1e-12f);
#pragma unroll
  for (int k = 0; k < 8; ++k) p[k] *= rinv;

  int jb = rp[u], je = rp[u + 1], deg = je - jb;

  for (int it = 0; it < 3; ++it) {
    float S = 0.f;
    float acc[8] = {0.f, 0.f, 0.f, 0.f, 0.f, 0.f, 0.f, 0.f};
    for (int i0 = 0; i0 < deg; i0 += 8) {
      int iA = i0 + sub, iB = i0 + 4 + sub;
      bool vA = iA < deg, vB = iB < deg;
      int jA = jb + (vA ? iA : 0), jB = jb + (vB ? iB : 0);
      uint4 uA, uB;
      if (it == 0) {
        int sA = srcs[jA], sB = srcs[jB];
        uA = *(const uint4*)&XVT[(size_t)sA * 128 + sl * 8];
        uB = *(const uint4*)&XVT[(size_t)sB * 128 + sl * 8];
        if (vA && iA < CAP) *(uint4*)&myc[iA * 128 + sl * 8] = uA;
        if (vB && iB < CAP) *(uint4*)&myc[iB * 128 + sl * 8] = uB;
      } else {
        int iiA = vA ? iA : 0, iiB = vB ? iB : 0;
        if (iiA < CAP) uA = *(const uint4*)&myc[iiA * 128 + sl * 8];
        else uA = *(const uint4*)&XVT[(size_t)srcs[jA] * 128 + sl * 8];
        if (iiB < CAP) uB = *(const uint4*)&myc[iiB * 128 + sl * 8];
        else uB = *(const uint4*)&XVT[(size_t)srcs[jB] * 128 + sl * 8];
      }
      float fA[8], fB[8];
      bf8_to_f32(uA, fA);
      bf8_to_f32(uB, fB);
      float dA = 0.f, dB = 0.f;
#pragma unroll
      for (int k = 0; k < 8; ++k) { dA += p[k] * fA[k]; dB += p[k] * fB[k]; }
      dA += __shfl_xor(dA, 1); dA += __shfl_xor(dA, 2); dA += __shfl_xor(dA, 4);
      dB += __shfl_xor(dB, 1); dB += __shfl_xor(dB, 2); dB += __shfl_xor(dB, 4);
      float eA = vA ? __expf(dA) : 0.f;
      float eB = vB ? __expf(dB) : 0.f;
      S += eA + eB;
#pragma unroll
      for (int k = 0; k < 8; ++k) acc[k] += eA * fA[k] + eB * fB[k];
    }
    S += __shfl_xor(S, 16); S += __shfl_xor(S, 32);
#pragma unroll
    for (int k = 0; k < 8; ++k) {
      acc[k] += __shfl_xor(acc[k], 16);
      acc[k] += __shfl_xor(acc[k], 32);
    }
    if (deg > 0) {
      float r = 1.f / S;
#pragma unroll
      for (int k = 0; k < 8; ++k) p[k] += acc[k] * r;
    }
    ss = 0.f;
#pragma unroll
    for (int k = 0; k < 8; ++k) ss += p[k] * p[k];
    ss += __shfl_xor(ss, 1); ss += __shfl_xor(ss, 2); ss += __shfl_xor(ss, 4);
    rinv = 1.f / fmaxf(sqrtf(ss), 1e-12f);
#pragma unroll
    for (int k = 0; k < 8; ++k) p[k] *= rinv;
  }

  // final GAT (user side)
  float S = 0.f;
  float acc[8] = {0.f, 0.f, 0.f, 0.f, 0.f, 0.f, 0.f, 0.f};
  for (int i0 = 0; i0 < deg; i0 += 8) {
    int iA = i0 + sub, iB = i0 + 4 + sub;
    bool vA = iA < deg, vB = iB < deg;
    int jA = jb + (vA ? iA : 0), jB = jb + (vB ? iB : 0);
    int sA = srcs[jA], sB = srcs[jB];
    int iiA = vA ? iA : 0, iiB = vB ? iB : 0;
    uint4 uA, uB;
    if (iiA < CAP) uA = *(const uint4*)&myc[iiA * 128 + sl * 8];
    else uA = *(const uint4*)&XVT[(size_t)sA * 128 + sl * 8];
    if (iiB < CAP) uB = *(const uint4*)&myc[iiB * 128 + sl * 8];
    else uB = *(const uint4*)&XVT[(size_t)sB * 128 + sl * 8];
    float fA[8], fB[8];
    bf8_to_f32(uA, fA);
    bf8_to_f32(uB, fB);
    float dA = 0.f, dB = 0.f;
#pragma unroll
    for (int k = 0; k < 8; ++k) { dA += p[k] * fA[k]; dB += p[k] * fB[k]; }
    dA += __shfl_xor(dA, 1); dA += __shfl_xor(dA, 2); dA += __shfl_xor(dA, 4);
    dB += __shfl_xor(dB, 1); dB += __shfl_xor(dB, 2); dB += __shfl_xor(dB, 4);
    float dAo = __shfl_xor(dA, 8), dBo = __shfl_xor(dB, 8);
    float eA = vA ? __expf(dA) : 0.f;
    float eB = vB ? __expf(dB) : 0.f;
    S += eA + eB;
#pragma unroll
    for (int k = 0; k < 8; ++k) acc[k] += eA * fA[k] + eB * fB[k];
    if (sl == 0) {
      if (vA) {
        float2 c = *(const float2*)&conf[2 * sA];
        float ae = eA * c.x, be = __expf(dAo) * c.y;
        Ae[jA] = ae; Be[jA] = be;
        if (iA < ESTN) { es[2 * iA] = ae; es[2 * iA + 1] = be; }
      }
      if (vB) {
        float2 c = *(const float2*)&conf[2 * sB];
        float ae = eB * c.x, be = __expf(dBo) * c.y;
        Ae[jB] = ae; Be[jB] = be;
        if (iB < ESTN) { es[2 * iB] = ae; es[2 * iB + 1] = be; }
      }
    }
  }
  S += __shfl_xor(S, 16); S += __shfl_xor(S, 32);
#pragma unroll
  for (int k = 0; k < 8; ++k) {
    acc[k] += __shfl_xor(acc[k], 16);
    acc[k] += __shfl_xor(acc[k], 32);
  }
  float So = __shfl_xor(S, 8);
  if (lane == 0) { SV[u] = S; ST[u] = So; }
  if (sub == 0) {
    float o[8];
    if (deg > 0) {
      float r = 1.f / S;
#pragma unroll
      for (int k = 0; k < 8; ++k) o[k] = p[k] + leaky(acc[k] * r);
    } else {
#pragma unroll
      for (int k = 0; k < 8; ++k) o[k] = p[k];
    }
    size_t ob = (size_t)u * 192 + 64 + half * 64 + e8 * 8;
    *(float4*)&out[ob] = *(float4*)&o[0];
    *(float4*)&out[ob + 4] = *(float4*)&o[4];
    *(uint4*)&XVT[(size_t)u * 128 + sl * 8] = f32_to_bf8(p);
  }

  // egcn_h1 for this user row
  float Sv = half ? So : S;
  float St_ = half ? S : So;
  float rv = (deg > 0) ? 0.5f / Sv : 0.f;
  float rt = (deg > 0) ? 0.5f / St_ : 0.f;
  float hacc[4] = {0.f, 0.f, 0.f, 0.f};
  for (int i0 = 0; i0 < deg; i0 += 8) {
    int iA = i0 + sub, iB = i0 + 4 + sub;
    bool vA = iA < deg, vB = iB < deg;
    int jA = jb + (vA ? iA : 0), jB = jb + (vB ? iB : 0);
    int sA = srcs[jA], sB = srcs[jB];
    uint2 gA = *(const uint2*)&X0b[(size_t)sA * 64 + sl * 4];
    uint2 gB = *(const uint2*)&X0b[(size_t)sB * 64 + sl * 4];
    int iiA = vA ? iA : 0, iiB = vB ? iB : 0;
    float aeA = (iiA < ESTN) ? es[2 * iiA] : Ae[jA];
    float beA = (iiA < ESTN) ? es[2 * iiA + 1] : Be[jA];
    float aeB = (iiB < ESTN) ? es[2 * iiB] : Ae[jB];
    float beB = (iiB < ESTN) ? es[2 * iiB + 1] : Be[jB];
    float wA = vA ? fmaxf(fmaxf(rv * aeA, rt * beA), 0.f) : 0.f;
    float wB = vB ? fmaxf(fmaxf(rv * aeB, rt * beB), 0.f) : 0.f;
    if (sl == 0) {
      if (vA) wE[jA] = wA;
      if (vB) wE[jB] = wB;
    }
    float fA[4], fB[4];
    bf4_to_f32(gA, fA);
    bf4_to_f32(gB, fB);
#pragma unroll
    for (int k = 0; k < 4; ++k) hacc[k] += wA * fA[k] + wB * fB[k];
  }
#pragma unroll
  for (int k = 0; k < 4; ++k) {
    hacc[k] += __shfl_xor(hacc[k], 16);
    hacc[k] += __shfl_xor(hacc[k], 32);
  }
  if (sub == 0) {
    float h[4] = {0.f, 0.f, 0.f, 0.f};
    if (deg > 0) {
      float r = 1.f / (float)deg;
#pragma unroll
      for (int k = 0; k < 4; ++k) h[k] = leaky(hacc[k] * r);
    }
    *(uint2*)&H1b[(size_t)u * 64 + sl * 4] = f32_to_bf4(h);
  }
}

// ---------------- item GAT + egcn_h1(item) ----------------
__global__ __launch_bounds__(256) void gat_item_kernel(
    const unsigned short* __restrict__ XVT, const unsigned short* __restrict__ X0b,
    const float* __restrict__ XVf, const float* __restrict__ XTf,
    const int* __restrict__ rp, const int* __restrict__ srcs,
    const float* __restrict__ conf,
    float* __restrict__ Ae, float* __restrict__ Be,
    float* __restrict__ SV, float* __restrict__ ST,
    float* __restrict__ wE, unsigned short* __restrict__ H1b,
    float* __restrict__ out) {
  __shared__ float estash[4][2 * ESTN];
  int wv = threadIdx.x >> 6;
  int wid = blockIdx.x * 4 + wv;
  if (wid >= NITEM) return;
  int lane = threadIdx.x & 63;
  int sub = lane >> 4, sl = lane & 15, half = sl >> 3, e8 = sl & 7;
  float* es = estash[wv];
  int row = NUSER + wid;
  const float* xsrc = half ? XTf : XVf;
  float xn[8];
  *(float4*)&xn[0] = *(const float4*)&xsrc[(size_t)wid * 64 + e8 * 8];
  *(float4*)&xn[4] = *(const float4*)&xsrc[(size_t)wid * 64 + e8 * 8 + 4];
  int jb = rp[row], je = rp[row + 1], deg = je - jb;
  float S = 0.f;
  float acc[8] = {0.f, 0.f, 0.f, 0.f, 0.f, 0.f, 0.f, 0.f};
  for (int i0 = 0; i0 < deg; i0 += 8) {
    int iA = i0 + sub, iB = i0 + 4 + sub;
    bool vA = iA < deg, vB = iB < deg;
    int jA = jb + (vA ? iA : 0), jB = jb + (vB ? iB : 0);
    int sA = srcs[jA], sB = srcs[jB];
    uint4 uA = *(const uint4*)&XVT[(size_t)sA * 128 + sl * 8];
    uint4 uB = *(const uint4*)&XVT[(size_t)sB * 128 + sl * 8];
    float fA[8], fB[8];
    bf8_to_f32(uA, fA);
    bf8_to_f32(uB, fB);
    float dA = 0.f, dB = 0.f;
#pragma unroll
    for (int k = 0; k < 8; ++k) { dA += xn[k] * fA[k]; dB += xn[k] * fB[k]; }
    dA += __shfl_xor(dA, 1); dA += __shfl_xor(dA, 2); dA += __shfl_xor(dA, 4);
    dB += __shfl_xor(dB, 1); dB += __shfl_xor(dB, 2); dB += __shfl_xor(dB, 4);
    float dAo = __shfl_xor(dA, 8), dBo = __shfl_xor(dB, 8);
    float eA = vA ? __expf(dA) : 0.f;
    float eB = vB ? __expf(dB) : 0.f;
    S += eA + eB;
#pragma unroll
    for (int k = 0; k < 8; ++k) acc[k] += eA * fA[k] + eB * fB[k];
    if (sl == 0) {
      if (vA) {
        float2 c = *(const float2*)&conf[2 * sA];
        float ae = eA * c.x, be = __expf(dAo) * c.y;
        Ae[jA] = ae; Be[jA] = be;
        if (iA < ESTN) { es[2 * iA] = ae; es[2 * iA + 1] = be; }
      }
      if (vB) {
        float2 c = *(const float2*)&conf[2 * sB];
        float ae = eB * c.x, be = __expf(dBo) * c.y;
        Ae[jB] = ae; Be[jB] = be;
        if (iB < ESTN) { es[2 * iB] = ae; es[2 * iB + 1] = be; }
      }
    }
  }
  S += __shfl_xor(S, 16); S += __shfl_xor(S, 32);
#pragma unroll
  for (int k = 0; k < 8; ++k) {
    acc[k] += __shfl_xor(acc[k], 16);
    acc[k] += __shfl_xor(acc[k], 32);
  }
  float So = __shfl_xor(S, 8);
  if (lane == 0) { SV[row] = S; ST[row] = So; }
  if (sub == 0) {
    float o[8];
    if (deg > 0) {
      float r = 1.f / S;
#pragma unroll
      for (int k = 0; k < 8; ++k) o[k] = xn[k] + leaky(acc[k] * r);
    } else {
#pragma unroll
      for (int k = 0; k < 8; ++k) o[k] = xn[k];
    }
    size_t ob = (size_t)row * 192 + 64 + half * 64 + e8 * 8;
    *(float4*)&out[ob] = *(float4*)&o[0];
    *(float4*)&out[ob + 4] = *(float4*)&o[4];
  }

  // egcn_h1 for this item row
  float Sv = half ? So : S;
  float St_ = half ? S : So;
  float rv = (deg > 0) ? 0.5f / Sv : 0.f;
  float rt = (deg > 0) ? 0.5f / St_ : 0.f;
  float hacc[4] = {0.f, 0.f, 0.f, 0.f};
  for (int i0 = 0; i0 < deg; i0 += 8) {
    int iA = i0 + sub, iB = i0 + 4 + sub;
    bool vA = iA < deg, vB = iB < deg;
    int jA = jb + (vA ? iA : 0), jB = jb + (vB ? iB : 0);
    int sA = srcs[jA], sB = srcs[jB];
    uint2 gA = *(const uint2*)&X0b[(size_t)sA * 64 + sl * 4];
    uint2 gB = *(const uint2*)&X0b[(size_t)sB * 64 + sl * 4];
    int iiA = vA ? iA : 0, iiB = vB ? iB : 0;
    float aeA = (iiA < ESTN) ? es[2 * iiA] : Ae[jA];
    float beA = (iiA < ESTN) ? es[2 * iiA + 1] : Be[jA];
    float aeB = (iiB < ESTN) ? es[2 * iiB] : Ae[jB];
    float beB = (iiB < ESTN) ? es[2 * iiB + 1] : Be[jB];
    float wA = vA ? fmaxf(fmaxf(rv * aeA, rt * beA), 0.f) : 0.f;
    float wB = vB ? fmaxf(fmaxf(rv * aeB, rt * beB), 0.f) : 0.f;
    if (sl == 0) {
      if (vA) wE[jA] = wA;
      if (vB) wE[jB] = wB;
    }
    float fA[4], fB[4];
    bf4_to_f32(gA, fA);
    bf4_to_f32(gB, fB);
#pragma unroll
    for (int k = 0; k < 4; ++k) hacc[k] += wA * fA[k] + wB * fB[k];
  }
#pragma unroll
  for (int k = 0; k < 4; ++k) {
    hacc[k] += __shfl_xor(hacc[k], 16);
    hacc[k] += __shfl_xor(hacc[k], 32);
  }
  if (sub == 0) {
    float h[4] = {0.f, 0.f, 0.f, 0.f};
    if (deg > 0) {
      float r = 1.f / (float)deg;
#pragma unroll
      for (int k = 0; k < 4; ++k) h[k] = leaky(hacc[k] * r);
    }
    *(uint2*)&H1b[(size_t)row * 64 + sl * 4] = f32_to_bf4(h);
  }
}

// ---------------- egcn hop 2 + id_rep write ----------------
__global__ __launch_bounds__(256) void egcn_h2_kernel(
    const float* __restrict__ x0, const unsigned short* __restrict__ H1b,
    const int* __restrict__ rp, const int* __restrict__ srcs,
    const float* __restrict__ wE, float* __restrict__ out) {
  int wid = (blockIdx.x * 256 + threadIdx.x) >> 6;
  if (wid >= NNODE) return;
  int lane = threadIdx.x & 63, sub = lane >> 4, sl = lane & 15;
  int jb = rp[wid], je = rp[wid + 1], deg = je - jb;
  float acc[4] = {0.f, 0.f, 0.f, 0.f};
  for (int i0 = 0; i0 < deg; i0 += 8) {
    int iA = i0 + sub, iB = i0 + 4 + sub;
    bool vA = iA < deg, vB = iB < deg;
    int jA = jb + (vA ? iA : 0), jB = jb + (vB ? iB : 0);
    int sA = srcs[jA], sB = srcs[jB];
    float wA = vA ? wE[jA] : 0.f;
    float wB = vB ? wE[jB] : 0.f;
    uint2 gA = *(const uint2*)&H1b[(size_t)sA * 64 + sl * 4];
    uint2 gB = *(const uint2*)&H1b[(size_t)sB * 64 + sl * 4];
    float fA[4], fB[4];
    bf4_to_f32(gA, fA);
    bf4_to_f32(gB, fB);
#pragma unroll
    for (int k = 0; k < 4; ++k) acc[k] += wA * fA[k] + wB * fB[k];
  }
#pragma unroll
  for (int k = 0; k < 4; ++k) {
    acc[k] += __shfl_xor(acc[k], 16);
    acc[k] += __shfl_xor(acc[k], 32);
  }
  if (sub == 0) {
    float h2[4] = {0.f, 0.f, 0.f, 0.f};
    if (deg > 0) {
      float r = 1.f / (float)deg;
#pragma unroll
      for (int k = 0; k < 4; ++k) h2[k] = leaky(acc[k] * r);
    }
    float4 a = *(const float4*)&x0[(size_t)wid * 64 + sl * 4];
    uint2 u2 = *(const uint2*)&H1b[(size_t)wid * 64 + sl * 4];
    float h1[4];
    bf4_to_f32(u2, h1);
    float4 o = {a.x + h1[0] + h2[0], a.y + h1[1] + h2[1],
                a.z + h1[2] + h2[2], a.w + h1[3] + h2[3]};
    *(float4*)&out[(size_t)wid * 192 + sl * 4] = o;
  }
}

// ---------------- launcher ----------------
extern "C" void kernel_launch(void* const* d_in, const int* in_sizes, int n_in,
                              void* d_out, int out_size, void* d_ws, size_t ws_size,
                              hipStream_t stream) {
  const int* ei = (const int*)d_in[0];
  const float* v_feat = (const float*)d_in[1];
  const float* t_feat = (const float*)d_in[2];
  const float* pref_v = (const float*)d_in[3];
  const float* pref_t = (const float*)d_in[4];
  const float* W_v = (const float*)d_in[5];
  const float* b_v = (const float*)d_in[6];
  const float* W_t = (const float*)d_in[7];
  const float* b_t = (const float*)d_in[8];
  const float* id_emb = (const float*)d_in[9];
  const float* conf = (const float*)d_in[10];
  float* out = (float*)d_out;

  float* ws = (float*)d_ws;
  unsigned short* XVT = (unsigned short*)(ws + O_XVT);
  float* x0 = ws + O_X0;
  unsigned short* X0b = (unsigned short*)(ws + O_X0B);
  unsigned short* H1b = (unsigned short*)(ws + O_H1B);
  float* XVf = ws + O_XVF;
  float* XTf = ws + O_XTF;
  float* Ae = ws + O_AE;
  float* Be = ws + O_BE;
  float* wE = ws + O_WE;
  float* SV = ws + O_SV;
  float* ST = ws + O_ST;
  int* deg = (int*)(ws + O_DEG);
  int* row_ptr = (int*)(ws + O_RP);
  int* fill = (int*)(ws + O_FILL);
  int* srcs = (int*)(ws + O_SRC);
  int* bsum = (int*)(ws + O_BSUM);
  short* wsp = (short*)(ws + O_WSPL);
  float* Pv = ws + O_PV;
  float* Pt = ws + O_PT;

  const int NB = (NNODE + 255) / 256;  // 352

  hipMemsetAsync(deg, 0, NNODE * sizeof(int), stream);
  wsplit_all_kernel<<<(2048 * 64 + 384 * 64 + 255) / 256, 256, 0, stream>>>(W_v, W_t, wsp);
  mega_prep_kernel<<<MEGA_BLOCKS, 256, 0, stream>>>(v_feat, t_feat, wsp, ei, deg,
                                                    id_emb, x0, X0b, Pv, Pt);
  scan_a_kernel<<<NB, 256, 0, stream>>>(deg, bsum);
  scan_b_kernel<<<NB, 256, 0, stream>>>(deg, bsum, row_ptr, fill);
  fill_epi_kernel<<<FE_FILL + 5000, 256, 0, stream>>>(ei, fill, srcs, Pv, Pt, b_v, b_t,
                                                      XVf, XTf, XVT);
  routing_user_kernel<<<NUSER / 4, 256, 0, stream>>>(pref_v, pref_t, XVT, X0b, row_ptr,
                                                     srcs, conf, Ae, Be, SV, ST, wE, H1b, out);
  gat_item_kernel<<<NITEM / 4, 256, 0, stream>>>(XVT, X0b, XVf, XTf, row_ptr, srcs, conf,
                                                 Ae, Be, SV, ST, wE, H1b, out);
  egcn_h2_kernel<<<NNODE / 4, 256, 0, stream>>>(x0, H1b, row_ptr, srcs, wE, out);
}